// Round 2
// baseline (728.400 us; speedup 1.0000x reference)
//
#include <hip/hip_runtime.h>
#include <hip/hip_bf16.h>

#define D 128
#define NN 40000
#define EE 640000
#define GG 8
#define NPG 5000

__device__ __forceinline__ float lrelu(float v) { return v >= 0.f ? v : 0.01f * v; }

// ---------------------------------------------------------------------------
// 64x64-tile fp32 GEMM pass: acc += A[tile rows, :] @ B[:, col half]
// A is [M,128] row-major, B is [128,128] row-major.
// AsT staged transposed [k][row] (stride 68 keeps float4 reads 16B-aligned,
// banks spread). Bs staged [k][col]. K processed in two 64-wide halves.
// ---------------------------------------------------------------------------
template <int LEAKY_A>
__device__ __forceinline__ void gemm_pass(const float* __restrict__ A,
                                          const float* __restrict__ B,
                                          float (&acc)[4][4],
                                          float (*AsT)[68], float (*Bs)[64],
                                          int arow, int c_off, int tid) {
    const int tx = tid & 15, ty = tid >> 4;
#pragma unroll
    for (int p = 0; p < 2; ++p) {
        const int k0 = p * 64;
        // stage A half (64 rows x 64 k), scalar loads (coalesced over k),
        // transposed scalar LDS writes: bank = (k + row) % 32 -> ~2-way.
#pragma unroll
        for (int i = 0; i < 16; ++i) {
            int flat = tid + i * 256;
            int kk = flat & 63, rr = flat >> 6;
            float a = A[(size_t)(arow + rr) * D + k0 + kk];
            if (LEAKY_A) a = lrelu(a);
            AsT[kk][rr] = a;
        }
        // stage B half (64 k x 64 cols), float4
#pragma unroll
        for (int i = 0; i < 4; ++i) {
            int flat = tid + i * 256;
            int rr = flat >> 4, c4 = flat & 15;
            *(float4*)&Bs[rr][c4 * 4] =
                *(const float4*)&B[(size_t)(k0 + rr) * D + c_off + c4 * 4];
        }
        __syncthreads();
#pragma unroll 8
        for (int k = 0; k < 64; ++k) {
            float4 a4 = *(const float4*)&AsT[k][ty * 4];
            float4 b4 = *(const float4*)&Bs[k][tx * 4];
            float a0 = a4.x, a1 = a4.y, a2 = a4.z, a3 = a4.w;
            float b0 = b4.x, b1 = b4.y, b2 = b4.z, b3 = b4.w;
            acc[0][0] += a0 * b0; acc[0][1] += a0 * b1; acc[0][2] += a0 * b2; acc[0][3] += a0 * b3;
            acc[1][0] += a1 * b0; acc[1][1] += a1 * b1; acc[1][2] += a1 * b2; acc[1][3] += a1 * b3;
            acc[2][0] += a2 * b0; acc[2][1] += a2 * b1; acc[2][2] += a2 * b2; acc[2][3] += a2 * b3;
            acc[3][0] += a3 * b0; acc[3][1] += a3 * b1; acc[3][2] += a3 * b2; acc[3][3] += a3 * b3;
        }
        __syncthreads();
    }
}

// C = [leaky?] ( op(A1)@B1 [+ op(A2)@B2] ), all [*,128]x[128,128]
template <int LEAKY_A1, int LEAKY_A2, int LEAKY_OUT, int TWO>
__global__ __launch_bounds__(256) void gemm_k(const float* __restrict__ A1,
                                              const float* __restrict__ B1,
                                              const float* __restrict__ A2,
                                              const float* __restrict__ B2,
                                              float* __restrict__ C) {
    __shared__ float AsT[64][68];
    __shared__ float Bs[64][64];
    const int tid = threadIdx.x;
    const int tile = blockIdx.x >> 1;
    const int c_off = (blockIdx.x & 1) * 64;
    const int arow = tile * 64;
    float acc[4][4] = {};
    gemm_pass<LEAKY_A1>(A1, B1, acc, AsT, Bs, arow, c_off, tid);
    if constexpr (TWO) gemm_pass<LEAKY_A2>(A2, B2, acc, AsT, Bs, arow, c_off, tid);

    const int tx = tid & 15, ty = tid >> 4;
#pragma unroll
    for (int i = 0; i < 4; ++i) {
        float4 o;
        o.x = acc[i][0]; o.y = acc[i][1]; o.z = acc[i][2]; o.w = acc[i][3];
        if (LEAKY_OUT) { o.x = lrelu(o.x); o.y = lrelu(o.y); o.z = lrelu(o.z); o.w = lrelu(o.w); }
        *(float4*)&C[(size_t)(arow + ty * 4 + i) * D + c_off + tx * 4] = o;
    }
}

// one wave per edge: xn[dst] += w[e] * h[src]
__global__ __launch_bounds__(256) void scatter_k(const float* __restrict__ h,
                                                 const int* __restrict__ ei,
                                                 const float* __restrict__ w,
                                                 float* __restrict__ xn) {
    const int e = (blockIdx.x << 2) + (threadIdx.x >> 6);
    const int lane = threadIdx.x & 63;
    const int dst = ei[e];
    const int src = ei[EE + e];
    const float we = w[e];
    float2 v = *((const float2*)(h + (size_t)src * D) + lane);
    float* xr = xn + (size_t)dst * D + lane * 2;
    atomicAdd(xr, v.x * we);
    atomicAdd(xr + 1, v.y * we);
}

// per-(graph, dim) sum and sumsq; grid = GG * 50 blocks, 100 rows per block
__global__ __launch_bounds__(256) void stats_k(const float* __restrict__ out,
                                               float* __restrict__ stats) {
    const int g = blockIdx.x / 50, chunk = blockIdx.x % 50;
    const int d = threadIdx.x & 127, half = threadIdx.x >> 7;
    size_t base = ((size_t)g * NPG + chunk * 100) * D + d;
    float s = 0.f, ss = 0.f;
#pragma unroll 4
    for (int r = half; r < 100; r += 2) {
        float v = out[base + (size_t)r * D];
        s += v; ss += v * v;
    }
    atomicAdd(&stats[g * D + d], s);
    atomicAdd(&stats[GG * D + g * D + d], ss);
}

__global__ __launch_bounds__(256) void norm_k(float* __restrict__ out,
                                              const float* __restrict__ stats,
                                              const float* __restrict__ gamma,
                                              const float* __restrict__ beta) {
    const int i4 = blockIdx.x * 256 + threadIdx.x;  // over NN*D/4
    const int row = i4 >> 5;
    const int g = row / NPG;
    const int d0 = (i4 & 31) * 4;
    float4 v = *((float4*)out + i4);
    const float4 s4 = *(const float4*)&stats[g * D + d0];
    const float4 q4 = *(const float4*)&stats[GG * D + g * D + d0];
    const float4 g4 = *(const float4*)&gamma[d0];
    const float4 b4 = *(const float4*)&beta[d0];
    const float inv = 1.f / (float)NPG;
    const float invm1 = 1.f / (float)(NPG - 1);
    float mu, var, sg;
    mu = s4.x * inv; var = (q4.x - s4.x * mu) * invm1; sg = sqrtf(fmaxf(var, 0.f));
    v.x = (v.x - mu) / (sg + 1e-6f) * g4.x + b4.x;
    mu = s4.y * inv; var = (q4.y - s4.y * mu) * invm1; sg = sqrtf(fmaxf(var, 0.f));
    v.y = (v.y - mu) / (sg + 1e-6f) * g4.y + b4.y;
    mu = s4.z * inv; var = (q4.z - s4.z * mu) * invm1; sg = sqrtf(fmaxf(var, 0.f));
    v.z = (v.z - mu) / (sg + 1e-6f) * g4.z + b4.z;
    mu = s4.w * inv; var = (q4.w - s4.w * mu) * invm1; sg = sqrtf(fmaxf(var, 0.f));
    v.w = (v.w - mu) / (sg + 1e-6f) * g4.w + b4.w;
    *((float4*)out + i4) = v;
}

extern "C" void kernel_launch(void* const* d_in, const int* in_sizes, int n_in,
                              void* d_out, int out_size, void* d_ws, size_t ws_size,
                              hipStream_t stream) {
    const float* x = (const float*)d_in[0];
    const int* ei = (const int*)d_in[1];
    const float* w = (const float*)d_in[2];
    // d_in[3] batch, d_in[4] batch_num: layout is fixed (contiguous 5000/graph)
    const float* W1 = (const float*)d_in[5];
    const float* W2 = (const float*)d_in[6];
    const float* Wo = (const float*)d_in[7];
    const float* Wn = (const float*)d_in[8];
    const float* gamma = (const float*)d_in[9];
    const float* beta = (const float*)d_in[10];
    float* out = (float*)d_out;

    char* ws = (char*)d_ws;
    const size_t MATB = (size_t)NN * D * sizeof(float);  // 20.48 MB
    float* tmp = (float*)ws;           // leaky(x@W1); later reused as xn
    float* h = (float*)(ws + MATB);    // tmp@W2
    float* stats = (float*)(ws + 2 * MATB);  // [2][GG][D]
    float* xn = tmp;                   // alias: tmp is dead after K2

    const int GEMM_GRID = (NN / 64) * 2;  // 1250

    // h = leaky(x@W1) @ W2
    gemm_k<0, 0, 1, 0><<<GEMM_GRID, 256, 0, stream>>>(x, W1, x, W1, tmp);
    gemm_k<0, 0, 0, 0><<<GEMM_GRID, 256, 0, stream>>>(tmp, W2, tmp, W2, h);
    // zero xn (aliases tmp; stream order makes this safe) and stats
    hipMemsetAsync(xn, 0, MATB, stream);
    hipMemsetAsync(stats, 0, 2 * GG * D * sizeof(float), stream);
    // xn += scatter(w * h[src] -> dst)
    scatter_k<<<EE / 4, 256, 0, stream>>>(h, ei, w, xn);
    // out = h@Wo + leaky(xn)@Wn
    gemm_k<0, 1, 0, 1><<<GEMM_GRID, 256, 0, stream>>>(h, Wo, xn, Wn, out);
    // GraphNorm
    stats_k<<<GG * 50, 256, 0, stream>>>(out, stats);
    norm_k<<<(NN * D / 4) / 256, 256, 0, stream>>>(out, stats, gamma, beta);
}

// Round 3
// 299.721 us; speedup vs baseline: 2.4303x; 2.4303x over previous
//
#include <hip/hip_runtime.h>
#include <hip/hip_bf16.h>

#define D 128
#define NN 40000
#define EE 640000
#define GG 8
#define NPG 5000
#define CAP 32          // CSR slots per node (deg ~ Poisson(16); overflow -> fallback list)
#define OVCAP 4096

__device__ __forceinline__ float lrelu(float v) { return v >= 0.f ? v : 0.01f * v; }

// ---------------------------------------------------------------------------
// 64x64-tile fp32 GEMM pass (unchanged from baseline)
// ---------------------------------------------------------------------------
template <int LEAKY_A>
__device__ __forceinline__ void gemm_pass(const float* __restrict__ A,
                                          const float* __restrict__ B,
                                          float (&acc)[4][4],
                                          float (*AsT)[68], float (*Bs)[64],
                                          int arow, int c_off, int tid) {
    const int tx = tid & 15, ty = tid >> 4;
#pragma unroll
    for (int p = 0; p < 2; ++p) {
        const int k0 = p * 64;
#pragma unroll
        for (int i = 0; i < 16; ++i) {
            int flat = tid + i * 256;
            int kk = flat & 63, rr = flat >> 6;
            float a = A[(size_t)(arow + rr) * D + k0 + kk];
            if (LEAKY_A) a = lrelu(a);
            AsT[kk][rr] = a;
        }
#pragma unroll
        for (int i = 0; i < 4; ++i) {
            int flat = tid + i * 256;
            int rr = flat >> 4, c4 = flat & 15;
            *(float4*)&Bs[rr][c4 * 4] =
                *(const float4*)&B[(size_t)(k0 + rr) * D + c_off + c4 * 4];
        }
        __syncthreads();
#pragma unroll 8
        for (int k = 0; k < 64; ++k) {
            float4 a4 = *(const float4*)&AsT[k][ty * 4];
            float4 b4 = *(const float4*)&Bs[k][tx * 4];
            float a0 = a4.x, a1 = a4.y, a2 = a4.z, a3 = a4.w;
            float b0 = b4.x, b1 = b4.y, b2 = b4.z, b3 = b4.w;
            acc[0][0] += a0 * b0; acc[0][1] += a0 * b1; acc[0][2] += a0 * b2; acc[0][3] += a0 * b3;
            acc[1][0] += a1 * b0; acc[1][1] += a1 * b1; acc[1][2] += a1 * b2; acc[1][3] += a1 * b3;
            acc[2][0] += a2 * b0; acc[2][1] += a2 * b1; acc[2][2] += a2 * b2; acc[2][3] += a2 * b3;
            acc[3][0] += a3 * b0; acc[3][1] += a3 * b1; acc[3][2] += a3 * b2; acc[3][3] += a3 * b3;
        }
        __syncthreads();
    }
}

template <int LEAKY_A1, int LEAKY_A2, int LEAKY_OUT, int TWO>
__global__ __launch_bounds__(256) void gemm_k(const float* __restrict__ A1,
                                              const float* __restrict__ B1,
                                              const float* __restrict__ A2,
                                              const float* __restrict__ B2,
                                              float* __restrict__ C) {
    __shared__ float AsT[64][68];
    __shared__ float Bs[64][64];
    const int tid = threadIdx.x;
    const int tile = blockIdx.x >> 1;
    const int c_off = (blockIdx.x & 1) * 64;
    const int arow = tile * 64;
    float acc[4][4] = {};
    gemm_pass<LEAKY_A1>(A1, B1, acc, AsT, Bs, arow, c_off, tid);
    if constexpr (TWO) gemm_pass<LEAKY_A2>(A2, B2, acc, AsT, Bs, arow, c_off, tid);

    const int tx = tid & 15, ty = tid >> 4;
#pragma unroll
    for (int i = 0; i < 4; ++i) {
        float4 o;
        o.x = acc[i][0]; o.y = acc[i][1]; o.z = acc[i][2]; o.w = acc[i][3];
        if (LEAKY_OUT) { o.x = lrelu(o.x); o.y = lrelu(o.y); o.z = lrelu(o.z); o.w = lrelu(o.w); }
        *(float4*)&C[(size_t)(arow + ty * 4 + i) * D + c_off + tx * 4] = o;
    }
}

// ---------------------------------------------------------------------------
// Scatter -> CSR-gather replacement (kills the 82M f32 atomics)
// ---------------------------------------------------------------------------
// fill: one thread per edge. Histogram + slot-claim via ONE int atomic/edge.
__global__ __launch_bounds__(256) void fill_k(const int* __restrict__ ei,
                                              const float* __restrict__ w,
                                              int* __restrict__ deg,
                                              int* __restrict__ csr_src,
                                              float* __restrict__ csr_w,
                                              int* __restrict__ ov) {
    const int e = blockIdx.x * 256 + threadIdx.x;
    const int dst = ei[e];
    const int src = ei[EE + e];
    const float we = w[e];
    const int pos = atomicAdd(&deg[dst], 1);
    if (pos < CAP) {
        csr_src[dst * CAP + pos] = src;
        csr_w[dst * CAP + pos] = we;
    } else {
        const int oi = atomicAdd(&ov[0], 1);
        if (oi < OVCAP) ov[1 + oi] = e;
    }
}

// gather: one wave per destination node; row accumulated in registers,
// written exactly once (no atomics, no xn pre-zeroing needed).
__global__ __launch_bounds__(256) void gather_k(const float* __restrict__ h,
                                                const int* __restrict__ deg,
                                                const int* __restrict__ csr_src,
                                                const float* __restrict__ csr_w,
                                                float* __restrict__ xn) {
    const int n = blockIdx.x * 4 + (threadIdx.x >> 6);
    const int lane = threadIdx.x & 63;
    int dn = deg[n];
    if (dn > CAP) dn = CAP;
    float2 acc = {0.f, 0.f};
#pragma unroll 2
    for (int j = 0; j < dn; ++j) {
        const int src = csr_src[n * CAP + j];
        const float wv = csr_w[n * CAP + j];
        const float2 v = *((const float2*)(h + (size_t)src * D) + lane);
        acc.x += wv * v.x;
        acc.y += wv * v.y;
    }
    *((float2*)(xn + (size_t)n * D) + lane) = acc;
}

// overflow edges (deg > CAP): atomic fallback; expected count ~0, cost ~0.
__global__ __launch_bounds__(256) void overflow_k(const float* __restrict__ h,
                                                  const int* __restrict__ ei,
                                                  const float* __restrict__ w,
                                                  const int* __restrict__ ov,
                                                  float* __restrict__ xn) {
    int cnt = ov[0];
    if (cnt > OVCAP) cnt = OVCAP;
    const int wid = threadIdx.x >> 6;
    const int lane = threadIdx.x & 63;
    for (int i = wid; i < cnt; i += 4) {
        const int e = ov[1 + i];
        const int dst = ei[e];
        const int src = ei[EE + e];
        const float we = w[e];
        const float2 v = *((const float2*)(h + (size_t)src * D) + lane);
        float* xr = xn + (size_t)dst * D + lane * 2;
        atomicAdd(xr, v.x * we);
        atomicAdd(xr + 1, v.y * we);
    }
}

// ---------------------------------------------------------------------------
// GraphNorm (unchanged)
// ---------------------------------------------------------------------------
__global__ __launch_bounds__(256) void stats_k(const float* __restrict__ out,
                                               float* __restrict__ stats) {
    const int g = blockIdx.x / 50, chunk = blockIdx.x % 50;
    const int d = threadIdx.x & 127, half = threadIdx.x >> 7;
    size_t base = ((size_t)g * NPG + chunk * 100) * D + d;
    float s = 0.f, ss = 0.f;
#pragma unroll 4
    for (int r = half; r < 100; r += 2) {
        float v = out[base + (size_t)r * D];
        s += v; ss += v * v;
    }
    atomicAdd(&stats[g * D + d], s);
    atomicAdd(&stats[GG * D + g * D + d], ss);
}

__global__ __launch_bounds__(256) void norm_k(float* __restrict__ out,
                                              const float* __restrict__ stats,
                                              const float* __restrict__ gamma,
                                              const float* __restrict__ beta) {
    const int i4 = blockIdx.x * 256 + threadIdx.x;
    const int row = i4 >> 5;
    const int g = row / NPG;
    const int d0 = (i4 & 31) * 4;
    float4 v = *((float4*)out + i4);
    const float4 s4 = *(const float4*)&stats[g * D + d0];
    const float4 q4 = *(const float4*)&stats[GG * D + g * D + d0];
    const float4 g4 = *(const float4*)&gamma[d0];
    const float4 b4 = *(const float4*)&beta[d0];
    const float inv = 1.f / (float)NPG;
    const float invm1 = 1.f / (float)(NPG - 1);
    float mu, var, sg;
    mu = s4.x * inv; var = (q4.x - s4.x * mu) * invm1; sg = sqrtf(fmaxf(var, 0.f));
    v.x = (v.x - mu) / (sg + 1e-6f) * g4.x + b4.x;
    mu = s4.y * inv; var = (q4.y - s4.y * mu) * invm1; sg = sqrtf(fmaxf(var, 0.f));
    v.y = (v.y - mu) / (sg + 1e-6f) * g4.y + b4.y;
    mu = s4.z * inv; var = (q4.z - s4.z * mu) * invm1; sg = sqrtf(fmaxf(var, 0.f));
    v.z = (v.z - mu) / (sg + 1e-6f) * g4.z + b4.z;
    mu = s4.w * inv; var = (q4.w - s4.w * mu) * invm1; sg = sqrtf(fmaxf(var, 0.f));
    v.w = (v.w - mu) / (sg + 1e-6f) * g4.w + b4.w;
    *((float4*)out + i4) = v;
}

extern "C" void kernel_launch(void* const* d_in, const int* in_sizes, int n_in,
                              void* d_out, int out_size, void* d_ws, size_t ws_size,
                              hipStream_t stream) {
    const float* x = (const float*)d_in[0];
    const int* ei = (const int*)d_in[1];
    const float* w = (const float*)d_in[2];
    const float* W1 = (const float*)d_in[5];
    const float* W2 = (const float*)d_in[6];
    const float* Wo = (const float*)d_in[7];
    const float* Wn = (const float*)d_in[8];
    const float* gamma = (const float*)d_in[9];
    const float* beta = (const float*)d_in[10];
    float* out = (float*)d_out;

    char* ws = (char*)d_ws;
    const size_t MATB = (size_t)NN * D * sizeof(float);   // 20.48 MB
    float* tmp = (float*)ws;                              // leaky(x@W1); later xn
    float* h = (float*)(ws + MATB);
    float* stats = (float*)(ws + 2 * MATB);               // [2][GG][D]
    size_t off = 2 * MATB + 8192;
    int* deg = (int*)(ws + off);          off += (size_t)NN * sizeof(int);       // 160 KB
    int* ov = (int*)(ws + off);           off += (size_t)(1 + OVCAP) * sizeof(int) + 252; off &= ~(size_t)255;
    int* csr_src = (int*)(ws + off);      off += (size_t)NN * CAP * sizeof(int); // 5.12 MB
    float* csr_w = (float*)(ws + off);    // 5.12 MB; total ~51.5 MB
    float* xn = tmp;                      // alias: tmp dead after K2

    const int GEMM_GRID = (NN / 64) * 2;  // 1250

    // h = leaky(x@W1) @ W2
    gemm_k<0, 0, 1, 0><<<GEMM_GRID, 256, 0, stream>>>(x, W1, x, W1, tmp);
    gemm_k<0, 0, 0, 0><<<GEMM_GRID, 256, 0, stream>>>(tmp, W2, tmp, W2, h);
    // CSR build + gather (replaces atomic scatter). deg/ov/stats zeroed each call.
    hipMemsetAsync(deg, 0, (size_t)NN * sizeof(int), stream);
    hipMemsetAsync(ov, 0, (size_t)(1 + OVCAP) * sizeof(int), stream);
    hipMemsetAsync(stats, 0, 2 * GG * D * sizeof(float), stream);
    fill_k<<<EE / 256, 256, 0, stream>>>(ei, w, deg, csr_src, csr_w, ov);
    gather_k<<<NN / 4, 256, 0, stream>>>(h, deg, csr_src, csr_w, xn);
    overflow_k<<<1, 256, 0, stream>>>(h, ei, w, ov, xn);
    // out = h@Wo + leaky(xn)@Wn
    gemm_k<0, 1, 0, 1><<<GEMM_GRID, 256, 0, stream>>>(h, Wo, xn, Wn, out);
    // GraphNorm
    stats_k<<<GG * 50, 256, 0, stream>>>(out, stats);
    norm_k<<<(NN * D / 4) / 256, 256, 0, stream>>>(out, stats, gamma, beta);
}

// Round 4
// 230.814 us; speedup vs baseline: 3.1558x; 1.2985x over previous
//
#include <hip/hip_runtime.h>
#include <hip/hip_bf16.h>

#define D 128
#define NN 40000
#define EE 640000
#define GG 8
#define NPG 5000
#define CAP 32          // CSR slots per node; overflow -> atomic fallback list
#define OVCAP 4096

using short8 = __attribute__((ext_vector_type(8))) short;  // 8 bf16 (4 VGPRs)
using f32x4 = __attribute__((ext_vector_type(4))) float;   // MFMA accumulator

__device__ __forceinline__ float lrelu(float v) { return v >= 0.f ? v : 0.01f * v; }

__device__ __forceinline__ ushort f2bf(float f) {  // RNE fp32 -> bf16 bits
    union { float f; uint u; } c; c.f = f;
    return (ushort)((c.u + 0x7FFFu + ((c.u >> 16) & 1u)) >> 16);
}
__device__ __forceinline__ float bf2f_lo(uint u) { union { uint u; float f; } c; c.u = u << 16; return c.f; }
__device__ __forceinline__ float bf2f_hi(uint u) { union { uint u; float f; } c; c.u = u & 0xFFFF0000u; return c.f; }

// ---------------------------------------------------------------------------
// Pre-transpose the 4 weight matrices to bf16 W^T[n][k] (so MFMA B-fragments
// read 8 contiguous k per lane). 128KB total, one-shot.
// ---------------------------------------------------------------------------
__global__ __launch_bounds__(256) void wtrans_k(const float* __restrict__ W1,
                                                const float* __restrict__ W2,
                                                const float* __restrict__ Wo,
                                                const float* __restrict__ Wn,
                                                short* __restrict__ WT) {
    const float* W = blockIdx.x == 0 ? W1 : blockIdx.x == 1 ? W2 : blockIdx.x == 2 ? Wo : Wn;
    short* T = WT + blockIdx.x * (D * D);
#pragma unroll 4
    for (int i = 0; i < 64; ++i) {
        int flat = threadIdx.x + i * 256;
        int k = flat >> 7, n = flat & 127;
        T[n * D + k] = (short)f2bf(W[flat]);
    }
}

// ---------------------------------------------------------------------------
// MFMA GEMM: C[64 rows x 128 cols per block] = A @ W (+ optional 2nd pass).
// As[64][136], Bs=W^T[128][136] bf16 in LDS; stride 136 -> 16B-aligned b128,
// <=2-way bank aliasing (free). 4 waves: wave w = rows [16w,16w+16), 8 n-tiles.
// ---------------------------------------------------------------------------
template <int ABF, int LKA>
__device__ __forceinline__ void mm_pass(const void* __restrict__ Av,
                                        const short* __restrict__ WT,
                                        short (*As)[136], short (*Bs)[136],
                                        f32x4 (&acc)[8], int arow, int tid) {
    // stage W^T (128x128 bf16), uint4 = 8 elems, fully coalesced
    const uint4* bsrc = (const uint4*)WT;
#pragma unroll
    for (int i = 0; i < 8; ++i) {
        int idx = tid + i * 256;
        int flat = idx * 8;
        *(uint4*)&Bs[flat >> 7][flat & 127] = bsrc[idx];
    }
    // stage A tile (64 rows x 128 k)
    if constexpr (ABF) {  // bf16 source
        const uint4* asrc = (const uint4*)Av;
#pragma unroll
        for (int i = 0; i < 4; ++i) {
            int idx = tid + i * 256;
            int flat = idx * 8;
            *(uint4*)&As[flat >> 7][flat & 127] = asrc[(size_t)arow * 16 + idx];
        }
    } else {  // fp32 source, convert (+optional leaky) while staging
        const float4* A4 = (const float4*)Av;
#pragma unroll
        for (int i = 0; i < 8; ++i) {
            int idx = tid + i * 256;
            int row = idx >> 5, kq = idx & 31;
            float4 v = A4[(size_t)(arow + row) * 32 + kq];
            if (LKA) { v.x = lrelu(v.x); v.y = lrelu(v.y); v.z = lrelu(v.z); v.w = lrelu(v.w); }
            uint2 p;
            p.x = (uint)f2bf(v.x) | ((uint)f2bf(v.y) << 16);
            p.y = (uint)f2bf(v.z) | ((uint)f2bf(v.w) << 16);
            *(uint2*)&As[row][kq * 4] = p;
        }
    }
    __syncthreads();
    const int lane = tid & 63;
    const int m0 = (tid >> 6) * 16;
    const int lrow = lane & 15;
    const int kgrp = (lane >> 4) * 8;
#pragma unroll
    for (int ks = 0; ks < 4; ++ks) {
        const int kb = ks * 32 + kgrp;
        short8 a = *(const short8*)&As[m0 + lrow][kb];
#pragma unroll
        for (int nt = 0; nt < 8; ++nt) {
            short8 b = *(const short8*)&Bs[nt * 16 + lrow][kb];
            acc[nt] = __builtin_amdgcn_mfma_f32_16x16x32_bf16(a, b, acc[nt], 0, 0, 0);
        }
    }
    __syncthreads();  // LDS reusable (2nd pass) after this
}

template <int A1BF, int LK1, int TWO, int A2BF, int LK2, int LKOUT, int CBF>
__global__ __launch_bounds__(256) void mm_k(const void* __restrict__ A1,
                                            const short* __restrict__ WT1,
                                            const void* __restrict__ A2,
                                            const short* __restrict__ WT2,
                                            void* __restrict__ Cv) {
    __shared__ short As[64][136];
    __shared__ short Bs[128][136];
    const int tid = threadIdx.x;
    const int arow = blockIdx.x * 64;
    f32x4 acc[8] = {};
    mm_pass<A1BF, LK1>(A1, WT1, As, Bs, acc, arow, tid);
    if constexpr (TWO) mm_pass<A2BF, LK2>(A2, WT2, As, Bs, acc, arow, tid);

    // C/D layout (m89-verified): col = lane&15, row = (lane>>4)*4 + reg
    const int lane = tid & 63;
    const int c0 = lane & 15;
    const int r0 = (tid >> 6) * 16 + ((lane >> 4) << 2);
#pragma unroll
    for (int nt = 0; nt < 8; ++nt) {
#pragma unroll
        for (int r = 0; r < 4; ++r) {
            float v = acc[nt][r];
            if (LKOUT) v = lrelu(v);
            const size_t off = (size_t)(arow + r0 + r) * D + nt * 16 + c0;
            if constexpr (CBF) ((ushort*)Cv)[off] = f2bf(v);
            else ((float*)Cv)[off] = v;
        }
    }
}

// ---------------------------------------------------------------------------
// CSR build + gather (h is bf16 now; xn stays fp32 for the atomic fallback)
// ---------------------------------------------------------------------------
__global__ __launch_bounds__(256) void fill_k(const int* __restrict__ ei,
                                              const float* __restrict__ w,
                                              int* __restrict__ deg,
                                              int* __restrict__ csr_src,
                                              float* __restrict__ csr_w,
                                              int* __restrict__ ov) {
    const int e = blockIdx.x * 256 + threadIdx.x;
    const int dst = ei[e];
    const int src = ei[EE + e];
    const float we = w[e];
    const int pos = atomicAdd(&deg[dst], 1);
    if (pos < CAP) {
        csr_src[dst * CAP + pos] = src;
        csr_w[dst * CAP + pos] = we;
    } else {
        const int oi = atomicAdd(&ov[0], 1);
        if (oi < OVCAP) ov[1 + oi] = e;
    }
}

__global__ __launch_bounds__(256) void gather_k(const ushort* __restrict__ h,
                                                const int* __restrict__ deg,
                                                const int* __restrict__ csr_src,
                                                const float* __restrict__ csr_w,
                                                float* __restrict__ xn) {
    const int n = blockIdx.x * 4 + (threadIdx.x >> 6);
    const int lane = threadIdx.x & 63;
    int dn = deg[n];
    if (dn > CAP) dn = CAP;
    float2 acc = {0.f, 0.f};
#pragma unroll 2
    for (int j = 0; j < dn; ++j) {
        const int src = csr_src[n * CAP + j];
        const float wv = csr_w[n * CAP + j];
        const uint v = *((const uint*)(h + (size_t)src * D) + lane);
        acc.x += wv * bf2f_lo(v);
        acc.y += wv * bf2f_hi(v);
    }
    *((float2*)(xn + (size_t)n * D) + lane) = acc;
}

__global__ __launch_bounds__(256) void overflow_k(const ushort* __restrict__ h,
                                                  const int* __restrict__ ei,
                                                  const float* __restrict__ w,
                                                  const int* __restrict__ ov,
                                                  float* __restrict__ xn) {
    int cnt = ov[0];
    if (cnt > OVCAP) cnt = OVCAP;
    const int wid = threadIdx.x >> 6;
    const int lane = threadIdx.x & 63;
    for (int i = wid; i < cnt; i += 4) {
        const int e = ov[1 + i];
        const int dst = ei[e];
        const int src = ei[EE + e];
        const float we = w[e];
        const uint v = *((const uint*)(h + (size_t)src * D) + lane);
        float* xr = xn + (size_t)dst * D + lane * 2;
        atomicAdd(xr, bf2f_lo(v) * we);
        atomicAdd(xr + 1, bf2f_hi(v) * we);
    }
}

// ---------------------------------------------------------------------------
// GraphNorm (unchanged; out is fp32)
// ---------------------------------------------------------------------------
__global__ __launch_bounds__(256) void stats_k(const float* __restrict__ out,
                                               float* __restrict__ stats) {
    const int g = blockIdx.x / 50, chunk = blockIdx.x % 50;
    const int d = threadIdx.x & 127, half = threadIdx.x >> 7;
    size_t base = ((size_t)g * NPG + chunk * 100) * D + d;
    float s = 0.f, ss = 0.f;
#pragma unroll 4
    for (int r = half; r < 100; r += 2) {
        float v = out[base + (size_t)r * D];
        s += v; ss += v * v;
    }
    atomicAdd(&stats[g * D + d], s);
    atomicAdd(&stats[GG * D + g * D + d], ss);
}

__global__ __launch_bounds__(256) void norm_k(float* __restrict__ out,
                                              const float* __restrict__ stats,
                                              const float* __restrict__ gamma,
                                              const float* __restrict__ beta) {
    const int i4 = blockIdx.x * 256 + threadIdx.x;
    const int row = i4 >> 5;
    const int g = row / NPG;
    const int d0 = (i4 & 31) * 4;
    float4 v = *((float4*)out + i4);
    const float4 s4 = *(const float4*)&stats[g * D + d0];
    const float4 q4 = *(const float4*)&stats[GG * D + g * D + d0];
    const float4 g4 = *(const float4*)&gamma[d0];
    const float4 b4 = *(const float4*)&beta[d0];
    const float inv = 1.f / (float)NPG;
    const float invm1 = 1.f / (float)(NPG - 1);
    float mu, var, sg;
    mu = s4.x * inv; var = (q4.x - s4.x * mu) * invm1; sg = sqrtf(fmaxf(var, 0.f));
    v.x = (v.x - mu) / (sg + 1e-6f) * g4.x + b4.x;
    mu = s4.y * inv; var = (q4.y - s4.y * mu) * invm1; sg = sqrtf(fmaxf(var, 0.f));
    v.y = (v.y - mu) / (sg + 1e-6f) * g4.y + b4.y;
    mu = s4.z * inv; var = (q4.z - s4.z * mu) * invm1; sg = sqrtf(fmaxf(var, 0.f));
    v.z = (v.z - mu) / (sg + 1e-6f) * g4.z + b4.z;
    mu = s4.w * inv; var = (q4.w - s4.w * mu) * invm1; sg = sqrtf(fmaxf(var, 0.f));
    v.w = (v.w - mu) / (sg + 1e-6f) * g4.w + b4.w;
    *((float4*)out + i4) = v;
}

extern "C" void kernel_launch(void* const* d_in, const int* in_sizes, int n_in,
                              void* d_out, int out_size, void* d_ws, size_t ws_size,
                              hipStream_t stream) {
    const float* x = (const float*)d_in[0];
    const int* ei = (const int*)d_in[1];
    const float* w = (const float*)d_in[2];
    const float* W1 = (const float*)d_in[5];
    const float* W2 = (const float*)d_in[6];
    const float* Wo = (const float*)d_in[7];
    const float* Wn = (const float*)d_in[8];
    const float* gamma = (const float*)d_in[9];
    const float* beta = (const float*)d_in[10];
    float* out = (float*)d_out;

    char* ws = (char*)d_ws;
    const size_t BF16MAT = (size_t)NN * D * 2;   // 10.24 MB
    const size_t F32MAT = (size_t)NN * D * 4;    // 20.48 MB
    size_t off = 0;
    ushort* t1 = (ushort*)(ws + off);  off += BF16MAT;                 // leaky(x@W1), bf16
    ushort* h = (ushort*)(ws + off);   off += BF16MAT;                 // t1@W2, bf16
    float* xn = (float*)(ws + off);    off += F32MAT;                  // fp32 (atomic fallback)
    float* stats = (float*)(ws + off); off += 2 * GG * D * 4 + 256;    // [2][G][D]
    short* WT = (short*)(ws + off);    off += 4 * (size_t)D * D * 2;   // 4x bf16 W^T
    int* deg = (int*)(ws + off);       off += (size_t)NN * 4;
    int* ov = (int*)(ws + off);        off += (1 + OVCAP) * 4 + 252; off &= ~(size_t)255;
    int* csr_src = (int*)(ws + off);   off += (size_t)NN * CAP * 4;
    float* csr_w = (float*)(ws + off);                                  // total ~51.6 MB

    const int MM_GRID = NN / 64;  // 625

    wtrans_k<<<4, 256, 0, stream>>>(W1, W2, Wo, Wn, WT);
    // t1 = leaky(x@W1)   [fp32 A, leaky on output, bf16 C]
    mm_k<0, 0, 0, 0, 0, 1, 1><<<MM_GRID, 256, 0, stream>>>(x, WT, x, WT, t1);
    // h = t1@W2          [bf16 A, bf16 C]
    mm_k<1, 0, 0, 1, 0, 0, 1><<<MM_GRID, 256, 0, stream>>>(t1, WT + D * D, t1, WT + D * D, h);
    // CSR build + gather
    hipMemsetAsync(deg, 0, (size_t)NN * 4, stream);
    hipMemsetAsync(ov, 0, (1 + OVCAP) * 4, stream);
    hipMemsetAsync(stats, 0, 2 * GG * D * 4, stream);
    fill_k<<<EE / 256, 256, 0, stream>>>(ei, w, deg, csr_src, csr_w, ov);
    gather_k<<<NN / 4, 256, 0, stream>>>(h, deg, csr_src, csr_w, xn);
    overflow_k<<<1, 256, 0, stream>>>(h, ei, w, ov, xn);
    // out = h@Wo + leaky(xn)@Wn   [pass1 bf16 A; pass2 fp32 A with leaky; fp32 C]
    mm_k<1, 0, 1, 0, 1, 0, 0><<<MM_GRID, 256, 0, stream>>>(h, WT + 2 * D * D, xn, WT + 3 * D * D, out);
    // GraphNorm
    stats_k<<<GG * 50, 256, 0, stream>>>(out, stats);
    norm_k<<<(NN * D / 4) / 256, 256, 0, stream>>>(out, stats, gamma, beta);
}

// Round 5
// 217.945 us; speedup vs baseline: 3.3421x; 1.0590x over previous
//
#include <hip/hip_runtime.h>
#include <hip/hip_bf16.h>

#define D 128
#define NN 40000
#define EE 640000
#define GG 8
#define NPG 5000
#define CAP 32          // CSR slots per node; overflow -> atomic fallback list
#define OVCAP 4096

using short8 = __attribute__((ext_vector_type(8))) short;  // 8 bf16 (4 VGPRs)
using f32x4 = __attribute__((ext_vector_type(4))) float;   // MFMA accumulator

__device__ __forceinline__ float lrelu(float v) { return v >= 0.f ? v : 0.01f * v; }

__device__ __forceinline__ ushort f2bf(float f) {  // RNE fp32 -> bf16 bits
    union { float f; uint u; } c; c.f = f;
    return (ushort)((c.u + 0x7FFFu + ((c.u >> 16) & 1u)) >> 16);
}
__device__ __forceinline__ float bf2f_lo(uint u) { union { uint u; float f; } c; c.u = u << 16; return c.f; }
__device__ __forceinline__ float bf2f_hi(uint u) { union { uint u; float f; } c; c.u = u & 0xFFFF0000u; return c.f; }

// ---------------------------------------------------------------------------
// Weight pre-transpose: bf16 W^T[n][k] so MFMA B-fragments read 8 contiguous k.
// ---------------------------------------------------------------------------
__global__ __launch_bounds__(256) void wtrans_k(const float* __restrict__ W1,
                                                const float* __restrict__ W2,
                                                const float* __restrict__ Wo,
                                                const float* __restrict__ Wn,
                                                short* __restrict__ WT) {
    const float* W = blockIdx.x == 0 ? W1 : blockIdx.x == 1 ? W2 : blockIdx.x == 2 ? Wo : Wn;
    short* T = WT + blockIdx.x * (D * D);
#pragma unroll 4
    for (int i = 0; i < 64; ++i) {
        int flat = threadIdx.x + i * 256;
        int k = flat >> 7, n = flat & 127;
        T[n * D + k] = (short)f2bf(W[flat]);
    }
}

// ---------------------------------------------------------------------------
// MFMA GEMM building blocks. As[64][136], Bs[128][136] bf16 in LDS
// (stride 136 -> 16B-aligned b128, <=2-way bank aliasing = free).
// 4 waves: wave w owns rows [16w,16w+16), 8 n-tiles of 16 cols.
// ---------------------------------------------------------------------------
__device__ __forceinline__ void stage_B(const short* __restrict__ WT,
                                        short (*Bs)[136], int tid) {
    const uint4* bsrc = (const uint4*)WT;
#pragma unroll
    for (int i = 0; i < 8; ++i) {
        int idx = tid + i * 256;
        int flat = idx * 8;
        *(uint4*)&Bs[flat >> 7][flat & 127] = bsrc[idx];
    }
}

template <int ABF, int LKA>
__device__ __forceinline__ void stage_A(const void* __restrict__ Av,
                                        short (*As)[136], int arow, int tid) {
    if constexpr (ABF) {  // bf16 source
        const uint4* asrc = (const uint4*)Av;
#pragma unroll
        for (int i = 0; i < 4; ++i) {
            int idx = tid + i * 256;
            int flat = idx * 8;
            *(uint4*)&As[flat >> 7][flat & 127] = asrc[(size_t)arow * 16 + idx];
        }
    } else {  // fp32 source, convert (+optional leaky) while staging
        const float4* A4 = (const float4*)Av;
#pragma unroll
        for (int i = 0; i < 8; ++i) {
            int idx = tid + i * 256;
            int row = idx >> 5, kq = idx & 31;
            float4 v = A4[(size_t)(arow + row) * 32 + kq];
            if (LKA) { v.x = lrelu(v.x); v.y = lrelu(v.y); v.z = lrelu(v.z); v.w = lrelu(v.w); }
            uint2 p;
            p.x = (uint)f2bf(v.x) | ((uint)f2bf(v.y) << 16);
            p.y = (uint)f2bf(v.z) | ((uint)f2bf(v.w) << 16);
            *(uint2*)&As[row][kq * 4] = p;
        }
    }
}

__device__ __forceinline__ void do_mfma(short (*As)[136], short (*Bs)[136],
                                        f32x4 (&acc)[8], int tid) {
    const int lane = tid & 63;
    const int m0 = (tid >> 6) * 16;
    const int lrow = lane & 15;
    const int kgrp = (lane >> 4) * 8;
#pragma unroll
    for (int ks = 0; ks < 4; ++ks) {
        const int kb = ks * 32 + kgrp;
        short8 a = *(const short8*)&As[m0 + lrow][kb];
#pragma unroll
        for (int nt = 0; nt < 8; ++nt) {
            short8 b = *(const short8*)&Bs[nt * 16 + lrow][kb];
            acc[nt] = __builtin_amdgcn_mfma_f32_16x16x32_bf16(a, b, acc[nt], 0, 0, 0);
        }
    }
}

// Fused MLP: h = leaky(x@W1) @ W2, t1 tile kept in LDS (As reused).
__global__ __launch_bounds__(256) void mlp_k(const float* __restrict__ x,
                                             const short* __restrict__ W1T,
                                             const short* __restrict__ W2T,
                                             ushort* __restrict__ h) {
    __shared__ short As[64][136];
    __shared__ short Bs[128][136];
    const int tid = threadIdx.x;
    const int arow = blockIdx.x * 64;
    f32x4 acc[8] = {};
    stage_A<0, 0>(x, As, arow, tid);
    stage_B(W1T, Bs, tid);
    __syncthreads();
    do_mfma(As, Bs, acc, tid);
    __syncthreads();  // As/Bs dead, safe to overwrite
    // t1 = leaky(acc) -> As (bf16, C-layout positions); stage W2T -> Bs
    const int lane = tid & 63;
    const int c0 = lane & 15;
    const int r0 = (tid >> 6) * 16 + ((lane >> 4) << 2);
#pragma unroll
    for (int nt = 0; nt < 8; ++nt)
#pragma unroll
        for (int r = 0; r < 4; ++r)
            As[r0 + r][nt * 16 + c0] = (short)f2bf(lrelu(acc[nt][r]));
    stage_B(W2T, Bs, tid);
#pragma unroll
    for (int nt = 0; nt < 8; ++nt) acc[nt] = f32x4{0.f, 0.f, 0.f, 0.f};
    __syncthreads();
    do_mfma(As, Bs, acc, tid);
#pragma unroll
    for (int nt = 0; nt < 8; ++nt)
#pragma unroll
        for (int r = 0; r < 4; ++r)
            h[(size_t)(arow + r0 + r) * D + nt * 16 + c0] = f2bf(acc[nt][r]);
}

// out = A1@W1T^T + leaky-staged(A2)@W2T^T  (pass1 bf16 A, pass2 fp32+leaky A)
template <int A1BF, int LK1, int TWO, int A2BF, int LK2, int LKOUT, int CBF>
__global__ __launch_bounds__(256) void mm_k(const void* __restrict__ A1,
                                            const short* __restrict__ WT1,
                                            const void* __restrict__ A2,
                                            const short* __restrict__ WT2,
                                            void* __restrict__ Cv) {
    __shared__ short As[64][136];
    __shared__ short Bs[128][136];
    const int tid = threadIdx.x;
    const int arow = blockIdx.x * 64;
    f32x4 acc[8] = {};
    stage_A<A1BF, LK1>(A1, As, arow, tid);
    stage_B(WT1, Bs, tid);
    __syncthreads();
    do_mfma(As, Bs, acc, tid);
    __syncthreads();
    if constexpr (TWO) {
        stage_A<A2BF, LK2>(A2, As, arow, tid);
        stage_B(WT2, Bs, tid);
        __syncthreads();
        do_mfma(As, Bs, acc, tid);
        __syncthreads();
    }
    // C/D layout (m89-verified): col = lane&15, row = (lane>>4)*4 + reg
    const int lane = tid & 63;
    const int c0 = lane & 15;
    const int r0 = (tid >> 6) * 16 + ((lane >> 4) << 2);
#pragma unroll
    for (int nt = 0; nt < 8; ++nt) {
#pragma unroll
        for (int r = 0; r < 4; ++r) {
            float v = acc[nt][r];
            if (LKOUT) v = lrelu(v);
            const size_t off = (size_t)(arow + r0 + r) * D + nt * 16 + c0;
            if constexpr (CBF) ((ushort*)Cv)[off] = f2bf(v);
            else ((float*)Cv)[off] = v;
        }
    }
}

// ---------------------------------------------------------------------------
// CSR build: ONE int2 8B store per edge (src,w interleaved -> shared lines)
// ---------------------------------------------------------------------------
__global__ __launch_bounds__(256) void fill_k(const int* __restrict__ ei,
                                              const float* __restrict__ w,
                                              int* __restrict__ deg,
                                              int2* __restrict__ csr,
                                              int* __restrict__ ov) {
    const int e = blockIdx.x * 256 + threadIdx.x;
    const int dst = ei[e];
    const int src = ei[EE + e];
    const float we = w[e];
    const int pos = atomicAdd(&deg[dst], 1);
    if (pos < CAP) {
        csr[dst * CAP + pos] = make_int2(src, __float_as_int(we));
    } else {
        const int oi = atomicAdd(&ov[0], 1);
        if (oi < OVCAP) ov[1 + oi] = e;
    }
}

// gather: one wave per node; 8/4/scalar chunked loop -> up to 8 outstanding
// h-row loads per wave (latency hiding), row written once, no atomics.
__global__ __launch_bounds__(256) void gather_k(const ushort* __restrict__ h,
                                                const int* __restrict__ deg,
                                                const int2* __restrict__ csr,
                                                float* __restrict__ xn) {
    const int n = blockIdx.x * 4 + (threadIdx.x >> 6);
    const int lane = threadIdx.x & 63;
    int dn = deg[n];
    if (dn > CAP) dn = CAP;
    const int2* row = csr + (size_t)n * CAP;
    float2 acc = {0.f, 0.f};
    int j = 0;
    for (; j + 8 <= dn; j += 8) {
        int2 p[8]; uint v[8];
#pragma unroll
        for (int t = 0; t < 8; ++t) p[t] = row[j + t];
#pragma unroll
        for (int t = 0; t < 8; ++t) v[t] = *((const uint*)(h + (size_t)p[t].x * D) + lane);
#pragma unroll
        for (int t = 0; t < 8; ++t) {
            const float wv = __int_as_float(p[t].y);
            acc.x += wv * bf2f_lo(v[t]);
            acc.y += wv * bf2f_hi(v[t]);
        }
    }
    if (j + 4 <= dn) {
        int2 p[4]; uint v[4];
#pragma unroll
        for (int t = 0; t < 4; ++t) p[t] = row[j + t];
#pragma unroll
        for (int t = 0; t < 4; ++t) v[t] = *((const uint*)(h + (size_t)p[t].x * D) + lane);
#pragma unroll
        for (int t = 0; t < 4; ++t) {
            const float wv = __int_as_float(p[t].y);
            acc.x += wv * bf2f_lo(v[t]);
            acc.y += wv * bf2f_hi(v[t]);
        }
        j += 4;
    }
    for (; j < dn; ++j) {
        int2 p = row[j];
        const uint v = *((const uint*)(h + (size_t)p.x * D) + lane);
        const float wv = __int_as_float(p.y);
        acc.x += wv * bf2f_lo(v);
        acc.y += wv * bf2f_hi(v);
    }
    *((float2*)(xn + (size_t)n * D) + lane) = acc;
}

__global__ __launch_bounds__(256) void overflow_k(const ushort* __restrict__ h,
                                                  const int* __restrict__ ei,
                                                  const float* __restrict__ w,
                                                  const int* __restrict__ ov,
                                                  float* __restrict__ xn) {
    int cnt = ov[0];
    if (cnt > OVCAP) cnt = OVCAP;
    const int wid = threadIdx.x >> 6;
    const int lane = threadIdx.x & 63;
    for (int i = wid; i < cnt; i += 4) {
        const int e = ov[1 + i];
        const int dst = ei[e];
        const int src = ei[EE + e];
        const float we = w[e];
        const uint v = *((const uint*)(h + (size_t)src * D) + lane);
        float* xr = xn + (size_t)dst * D + lane * 2;
        atomicAdd(xr, bf2f_lo(v) * we);
        atomicAdd(xr + 1, bf2f_hi(v) * we);
    }
}

// ---------------------------------------------------------------------------
// GraphNorm
// ---------------------------------------------------------------------------
__global__ __launch_bounds__(256) void stats_k(const float* __restrict__ out,
                                               float* __restrict__ stats) {
    const int g = blockIdx.x / 50, chunk = blockIdx.x % 50;
    const int d = threadIdx.x & 127, half = threadIdx.x >> 7;
    size_t base = ((size_t)g * NPG + chunk * 100) * D + d;
    float s = 0.f, ss = 0.f;
#pragma unroll 4
    for (int r = half; r < 100; r += 2) {
        float v = out[base + (size_t)r * D];
        s += v; ss += v * v;
    }
    atomicAdd(&stats[g * D + d], s);
    atomicAdd(&stats[GG * D + g * D + d], ss);
}

__global__ __launch_bounds__(256) void norm_k(float* __restrict__ out,
                                              const float* __restrict__ stats,
                                              const float* __restrict__ gamma,
                                              const float* __restrict__ beta) {
    const int i4 = blockIdx.x * 256 + threadIdx.x;
    const int row = i4 >> 5;
    const int g = row / NPG;
    const int d0 = (i4 & 31) * 4;
    float4 v = *((float4*)out + i4);
    const float4 s4 = *(const float4*)&stats[g * D + d0];
    const float4 q4 = *(const float4*)&stats[GG * D + g * D + d0];
    const float4 g4 = *(const float4*)&gamma[d0];
    const float4 b4 = *(const float4*)&beta[d0];
    const float inv = 1.f / (float)NPG;
    const float invm1 = 1.f / (float)(NPG - 1);
    float mu, var, sg;
    mu = s4.x * inv; var = (q4.x - s4.x * mu) * invm1; sg = sqrtf(fmaxf(var, 0.f));
    v.x = (v.x - mu) / (sg + 1e-6f) * g4.x + b4.x;
    mu = s4.y * inv; var = (q4.y - s4.y * mu) * invm1; sg = sqrtf(fmaxf(var, 0.f));
    v.y = (v.y - mu) / (sg + 1e-6f) * g4.y + b4.y;
    mu = s4.z * inv; var = (q4.z - s4.z * mu) * invm1; sg = sqrtf(fmaxf(var, 0.f));
    v.z = (v.z - mu) / (sg + 1e-6f) * g4.z + b4.z;
    mu = s4.w * inv; var = (q4.w - s4.w * mu) * invm1; sg = sqrtf(fmaxf(var, 0.f));
    v.w = (v.w - mu) / (sg + 1e-6f) * g4.w + b4.w;
    *((float4*)out + i4) = v;
}

extern "C" void kernel_launch(void* const* d_in, const int* in_sizes, int n_in,
                              void* d_out, int out_size, void* d_ws, size_t ws_size,
                              hipStream_t stream) {
    const float* x = (const float*)d_in[0];
    const int* ei = (const int*)d_in[1];
    const float* w = (const float*)d_in[2];
    const float* W1 = (const float*)d_in[5];
    const float* W2 = (const float*)d_in[6];
    const float* Wo = (const float*)d_in[7];
    const float* Wn = (const float*)d_in[8];
    const float* gamma = (const float*)d_in[9];
    const float* beta = (const float*)d_in[10];
    float* out = (float*)d_out;

    char* ws = (char*)d_ws;
    const size_t BF16MAT = (size_t)NN * D * 2;   // 10.24 MB
    const size_t F32MAT = (size_t)NN * D * 4;    // 20.48 MB
    size_t off = 0;
    ushort* h = (ushort*)(ws + off);   off += BF16MAT;                 // bf16
    float* xn = (float*)(ws + off);    off += F32MAT;                  // fp32
    float* stats = (float*)(ws + off); off += 2 * GG * D * 4 + 256;
    short* WT = (short*)(ws + off);    off += 4 * (size_t)D * D * 2;
    int* deg = (int*)(ws + off);       off += (size_t)NN * 4;
    int* ov = (int*)(ws + off);        off += (1 + OVCAP) * 4 + 252; off &= ~(size_t)255;
    int2* csr = (int2*)(ws + off);     // NN*CAP*8 = 10.24 MB; total ~41.5 MB

    const int MM_GRID = NN / 64;  // 625

    wtrans_k<<<4, 256, 0, stream>>>(W1, W2, Wo, Wn, WT);
    // h = leaky(x@W1) @ W2 (fused, t1 lives in LDS)
    mlp_k<<<MM_GRID, 256, 0, stream>>>(x, WT, WT + D * D, h);
    // CSR build + gather
    hipMemsetAsync(deg, 0, (size_t)NN * 4, stream);
    hipMemsetAsync(ov, 0, (1 + OVCAP) * 4, stream);
    hipMemsetAsync(stats, 0, 2 * GG * D * 4, stream);
    fill_k<<<EE / 256, 256, 0, stream>>>(ei, w, deg, csr, ov);
    gather_k<<<NN / 4, 256, 0, stream>>>(h, deg, csr, xn);
    overflow_k<<<1, 256, 0, stream>>>(h, ei, w, ov, xn);
    // out = h@Wo + leaky(xn)@Wn
    mm_k<1, 0, 1, 0, 1, 0, 0><<<MM_GRID, 256, 0, stream>>>(h, WT + 2 * D * D, xn, WT + 3 * D * D, out);
    // GraphNorm
    stats_k<<<GG * 50, 256, 0, stream>>>(out, stats);
    norm_k<<<(NN * D / 4) / 256, 256, 0, stream>>>(out, stats, gamma, beta);
}

// Round 6
// 213.996 us; speedup vs baseline: 3.4038x; 1.0185x over previous
//
#include <hip/hip_runtime.h>
#include <hip/hip_bf16.h>

#define D 128
#define NN 40000
#define EE 640000
#define GG 8
#define NPG 5000
#define CAP 32          // CSR slots per node; overflow -> atomic fallback list
#define OVCAP 4096

using short8 = __attribute__((ext_vector_type(8))) short;  // 8 bf16 (4 VGPRs)
using f32x4 = __attribute__((ext_vector_type(4))) float;   // MFMA accumulator

__device__ __forceinline__ float lrelu(float v) { return v >= 0.f ? v : 0.01f * v; }

__device__ __forceinline__ ushort f2bf(float f) {  // RNE fp32 -> bf16 bits
    union { float f; uint u; } c; c.f = f;
    return (ushort)((c.u + 0x7FFFu + ((c.u >> 16) & 1u)) >> 16);
}
__device__ __forceinline__ float bf2f_lo(uint u) { union { uint u; float f; } c; c.u = u << 16; return c.f; }
__device__ __forceinline__ float bf2f_hi(uint u) { union { uint u; float f; } c; c.u = u & 0xFFFF0000u; return c.f; }

// ---------------------------------------------------------------------------
// Weight pre-transpose: bf16 W^T[n][k] so MFMA B-fragments read 8 contiguous k.
// ---------------------------------------------------------------------------
__global__ __launch_bounds__(256) void wtrans_k(const float* __restrict__ W1,
                                                const float* __restrict__ W2,
                                                const float* __restrict__ Wo,
                                                const float* __restrict__ Wn,
                                                short* __restrict__ WT) {
    const float* W = blockIdx.x == 0 ? W1 : blockIdx.x == 1 ? W2 : blockIdx.x == 2 ? Wo : Wn;
    short* T = WT + blockIdx.x * (D * D);
#pragma unroll 4
    for (int i = 0; i < 64; ++i) {
        int flat = threadIdx.x + i * 256;
        int k = flat >> 7, n = flat & 127;
        T[n * D + k] = (short)f2bf(W[flat]);
    }
}

// ---------------------------------------------------------------------------
// MFMA GEMM building blocks. As[64][136], Bs[128][136] bf16 in LDS
// (stride 136 -> 16B-aligned b128, <=2-way bank aliasing = free).
// 4 waves: wave w owns rows [16w,16w+16), 8 n-tiles of 16 cols.
// ---------------------------------------------------------------------------
__device__ __forceinline__ void stage_B(const short* __restrict__ WT,
                                        short (*Bs)[136], int tid) {
    const uint4* bsrc = (const uint4*)WT;
#pragma unroll
    for (int i = 0; i < 8; ++i) {
        int idx = tid + i * 256;
        int flat = idx * 8;
        *(uint4*)&Bs[flat >> 7][flat & 127] = bsrc[idx];
    }
}

template <int ABF, int LKA>
__device__ __forceinline__ void stage_A(const void* __restrict__ Av,
                                        short (*As)[136], int arow, int tid) {
    if constexpr (ABF) {  // bf16 source
        const uint4* asrc = (const uint4*)Av;
#pragma unroll
        for (int i = 0; i < 4; ++i) {
            int idx = tid + i * 256;
            int flat = idx * 8;
            *(uint4*)&As[flat >> 7][flat & 127] = asrc[(size_t)arow * 16 + idx];
        }
    } else {  // fp32 source, convert (+optional leaky) while staging
        const float4* A4 = (const float4*)Av;
#pragma unroll
        for (int i = 0; i < 8; ++i) {
            int idx = tid + i * 256;
            int row = idx >> 5, kq = idx & 31;
            float4 v = A4[(size_t)(arow + row) * 32 + kq];
            if (LKA) { v.x = lrelu(v.x); v.y = lrelu(v.y); v.z = lrelu(v.z); v.w = lrelu(v.w); }
            uint2 p;
            p.x = (uint)f2bf(v.x) | ((uint)f2bf(v.y) << 16);
            p.y = (uint)f2bf(v.z) | ((uint)f2bf(v.w) << 16);
            *(uint2*)&As[row][kq * 4] = p;
        }
    }
}

__device__ __forceinline__ void do_mfma(short (*As)[136], short (*Bs)[136],
                                        f32x4 (&acc)[8], int tid) {
    const int lane = tid & 63;
    const int m0 = (tid >> 6) * 16;
    const int lrow = lane & 15;
    const int kgrp = (lane >> 4) * 8;
#pragma unroll
    for (int ks = 0; ks < 4; ++ks) {
        const int kb = ks * 32 + kgrp;
        short8 a = *(const short8*)&As[m0 + lrow][kb];
#pragma unroll
        for (int nt = 0; nt < 8; ++nt) {
            short8 b = *(const short8*)&Bs[nt * 16 + lrow][kb];
            acc[nt] = __builtin_amdgcn_mfma_f32_16x16x32_bf16(a, b, acc[nt], 0, 0, 0);
        }
    }
}

// Fused MLP: h = leaky(x@W1) @ W2, t1 tile kept in LDS (As reused).
__global__ __launch_bounds__(256) void mlp_k(const float* __restrict__ x,
                                             const short* __restrict__ W1T,
                                             const short* __restrict__ W2T,
                                             ushort* __restrict__ h) {
    __shared__ short As[64][136];
    __shared__ short Bs[128][136];
    const int tid = threadIdx.x;
    const int arow = blockIdx.x * 64;
    f32x4 acc[8] = {};
    stage_A<0, 0>(x, As, arow, tid);
    stage_B(W1T, Bs, tid);
    __syncthreads();
    do_mfma(As, Bs, acc, tid);
    __syncthreads();  // As/Bs dead, safe to overwrite
    // t1 = leaky(acc) -> As (bf16, C-layout positions); stage W2T -> Bs
    const int lane = tid & 63;
    const int c0 = lane & 15;
    const int r0 = (tid >> 6) * 16 + ((lane >> 4) << 2);
#pragma unroll
    for (int nt = 0; nt < 8; ++nt)
#pragma unroll
        for (int r = 0; r < 4; ++r)
            As[r0 + r][nt * 16 + c0] = (short)f2bf(lrelu(acc[nt][r]));
    stage_B(W2T, Bs, tid);
#pragma unroll
    for (int nt = 0; nt < 8; ++nt) acc[nt] = f32x4{0.f, 0.f, 0.f, 0.f};
    __syncthreads();
    do_mfma(As, Bs, acc, tid);
#pragma unroll
    for (int nt = 0; nt < 8; ++nt)
#pragma unroll
        for (int r = 0; r < 4; ++r)
            h[(size_t)(arow + r0 + r) * D + nt * 16 + c0] = f2bf(acc[nt][r]);
}

// out = A1@W1T^T + leaky-staged(A2)@W2T^T  (pass1 bf16 A, pass2 fp32+leaky A)
template <int A1BF, int LK1, int TWO, int A2BF, int LK2, int LKOUT, int CBF>
__global__ __launch_bounds__(256) void mm_k(const void* __restrict__ A1,
                                            const short* __restrict__ WT1,
                                            const void* __restrict__ A2,
                                            const short* __restrict__ WT2,
                                            void* __restrict__ Cv) {
    __shared__ short As[64][136];
    __shared__ short Bs[128][136];
    const int tid = threadIdx.x;
    const int arow = blockIdx.x * 64;
    f32x4 acc[8] = {};
    stage_A<A1BF, LK1>(A1, As, arow, tid);
    stage_B(WT1, Bs, tid);
    __syncthreads();
    do_mfma(As, Bs, acc, tid);
    __syncthreads();
    if constexpr (TWO) {
        stage_A<A2BF, LK2>(A2, As, arow, tid);
        stage_B(WT2, Bs, tid);
        __syncthreads();
        do_mfma(As, Bs, acc, tid);
        __syncthreads();
    }
    // C/D layout (m89-verified): col = lane&15, row = (lane>>4)*4 + reg
    const int lane = tid & 63;
    const int c0 = lane & 15;
    const int r0 = (tid >> 6) * 16 + ((lane >> 4) << 2);
#pragma unroll
    for (int nt = 0; nt < 8; ++nt) {
#pragma unroll
        for (int r = 0; r < 4; ++r) {
            float v = acc[nt][r];
            if (LKOUT) v = lrelu(v);
            const size_t off = (size_t)(arow + r0 + r) * D + nt * 16 + c0;
            if constexpr (CBF) ((ushort*)Cv)[off] = f2bf(v);
            else ((float*)Cv)[off] = v;
        }
    }
}

// ---------------------------------------------------------------------------
// CSR build: 4 edges/thread. Coalesced int4/float4 reads, 4 INDEPENDENT
// atomics issued back-to-back (latency overlap), then 4 stores.
// ---------------------------------------------------------------------------
__global__ __launch_bounds__(256) void fill_k(const int* __restrict__ ei,
                                              const float* __restrict__ w,
                                              int* __restrict__ deg,
                                              int2* __restrict__ csr,
                                              int* __restrict__ ov) {
    const int t = blockIdx.x * 256 + threadIdx.x;   // EE/4 threads
    const int e0 = t * 4;
    const int4 dst = *(const int4*)&ei[e0];
    const int4 src = *(const int4*)&ei[EE + e0];
    const float4 wv = *(const float4*)&w[e0];
    int pos[4];
    pos[0] = atomicAdd(&deg[dst.x], 1);
    pos[1] = atomicAdd(&deg[dst.y], 1);
    pos[2] = atomicAdd(&deg[dst.z], 1);
    pos[3] = atomicAdd(&deg[dst.w], 1);
    const int ds[4] = {dst.x, dst.y, dst.z, dst.w};
    const int sr[4] = {src.x, src.y, src.z, src.w};
    const float wf[4] = {wv.x, wv.y, wv.z, wv.w};
#pragma unroll
    for (int t4 = 0; t4 < 4; ++t4) {
        if (pos[t4] < CAP) {
            csr[ds[t4] * CAP + pos[t4]] = make_int2(sr[t4], __float_as_int(wf[t4]));
        } else {
            const int oi = atomicAdd(&ov[0], 1);
            if (oi < OVCAP) ov[1 + oi] = e0 + t4;
        }
    }
}

// gather: 32-lane half-wave per node (uint2 = 4 bf16 per lane), 8-deep
// batched loads -> 2 nodes' row-loads in flight per wave.
__global__ __launch_bounds__(256) void gather_k(const ushort* __restrict__ h,
                                                const int* __restrict__ deg,
                                                const int2* __restrict__ csr,
                                                float* __restrict__ xn) {
    const int n = blockIdx.x * 8 + (threadIdx.x >> 5);
    const int lane = threadIdx.x & 31;
    int dn = deg[n];
    if (dn > CAP) dn = CAP;
    const int2* row = csr + (size_t)n * CAP;
    float4 acc = {0.f, 0.f, 0.f, 0.f};
    int j = 0;
    for (; j + 8 <= dn; j += 8) {
        int2 p[8]; uint2 v[8];
#pragma unroll
        for (int t = 0; t < 8; ++t) p[t] = row[j + t];
#pragma unroll
        for (int t = 0; t < 8; ++t) v[t] = *((const uint2*)(h + (size_t)p[t].x * D) + lane);
#pragma unroll
        for (int t = 0; t < 8; ++t) {
            const float wv = __int_as_float(p[t].y);
            acc.x += wv * bf2f_lo(v[t].x);
            acc.y += wv * bf2f_hi(v[t].x);
            acc.z += wv * bf2f_lo(v[t].y);
            acc.w += wv * bf2f_hi(v[t].y);
        }
    }
    if (j + 4 <= dn) {
        int2 p[4]; uint2 v[4];
#pragma unroll
        for (int t = 0; t < 4; ++t) p[t] = row[j + t];
#pragma unroll
        for (int t = 0; t < 4; ++t) v[t] = *((const uint2*)(h + (size_t)p[t].x * D) + lane);
#pragma unroll
        for (int t = 0; t < 4; ++t) {
            const float wv = __int_as_float(p[t].y);
            acc.x += wv * bf2f_lo(v[t].x);
            acc.y += wv * bf2f_hi(v[t].x);
            acc.z += wv * bf2f_lo(v[t].y);
            acc.w += wv * bf2f_hi(v[t].y);
        }
        j += 4;
    }
    for (; j < dn; ++j) {
        int2 p = row[j];
        const uint2 v = *((const uint2*)(h + (size_t)p.x * D) + lane);
        const float wv = __int_as_float(p.y);
        acc.x += wv * bf2f_lo(v.x);
        acc.y += wv * bf2f_hi(v.x);
        acc.z += wv * bf2f_lo(v.y);
        acc.w += wv * bf2f_hi(v.y);
    }
    *((float4*)(xn + (size_t)n * D) + lane) = acc;
}

__global__ __launch_bounds__(256) void overflow_k(const ushort* __restrict__ h,
                                                  const int* __restrict__ ei,
                                                  const float* __restrict__ w,
                                                  const int* __restrict__ ov,
                                                  float* __restrict__ xn) {
    int cnt = ov[0];
    if (cnt > OVCAP) cnt = OVCAP;
    const int wid = threadIdx.x >> 6;
    const int lane = threadIdx.x & 63;
    for (int i = wid; i < cnt; i += 4) {
        const int e = ov[1 + i];
        const int dst = ei[e];
        const int src = ei[EE + e];
        const float we = w[e];
        const uint v = *((const uint*)(h + (size_t)src * D) + lane);
        float* xr = xn + (size_t)dst * D + lane * 2;
        atomicAdd(xr, bf2f_lo(v) * we);
        atomicAdd(xr + 1, bf2f_hi(v) * we);
    }
}

// ---------------------------------------------------------------------------
// GraphNorm
// ---------------------------------------------------------------------------
__global__ __launch_bounds__(256) void stats_k(const float* __restrict__ out,
                                               float* __restrict__ stats) {
    const int g = blockIdx.x / 50, chunk = blockIdx.x % 50;
    const int d = threadIdx.x & 127, half = threadIdx.x >> 7;
    size_t base = ((size_t)g * NPG + chunk * 100) * D + d;
    float s = 0.f, ss = 0.f;
#pragma unroll 4
    for (int r = half; r < 100; r += 2) {
        float v = out[base + (size_t)r * D];
        s += v; ss += v * v;
    }
    atomicAdd(&stats[g * D + d], s);
    atomicAdd(&stats[GG * D + g * D + d], ss);
}

__global__ __launch_bounds__(256) void norm_k(float* __restrict__ out,
                                              const float* __restrict__ stats,
                                              const float* __restrict__ gamma,
                                              const float* __restrict__ beta) {
    const int i4 = blockIdx.x * 256 + threadIdx.x;
    const int row = i4 >> 5;
    const int g = row / NPG;
    const int d0 = (i4 & 31) * 4;
    float4 v = *((float4*)out + i4);
    const float4 s4 = *(const float4*)&stats[g * D + d0];
    const float4 q4 = *(const float4*)&stats[GG * D + g * D + d0];
    const float4 g4 = *(const float4*)&gamma[d0];
    const float4 b4 = *(const float4*)&beta[d0];
    const float inv = 1.f / (float)NPG;
    const float invm1 = 1.f / (float)(NPG - 1);
    float mu, var, sg;
    mu = s4.x * inv; var = (q4.x - s4.x * mu) * invm1; sg = sqrtf(fmaxf(var, 0.f));
    v.x = (v.x - mu) / (sg + 1e-6f) * g4.x + b4.x;
    mu = s4.y * inv; var = (q4.y - s4.y * mu) * invm1; sg = sqrtf(fmaxf(var, 0.f));
    v.y = (v.y - mu) / (sg + 1e-6f) * g4.y + b4.y;
    mu = s4.z * inv; var = (q4.z - s4.z * mu) * invm1; sg = sqrtf(fmaxf(var, 0.f));
    v.z = (v.z - mu) / (sg + 1e-6f) * g4.z + b4.z;
    mu = s4.w * inv; var = (q4.w - s4.w * mu) * invm1; sg = sqrtf(fmaxf(var, 0.f));
    v.w = (v.w - mu) / (sg + 1e-6f) * g4.w + b4.w;
    *((float4*)out + i4) = v;
}

extern "C" void kernel_launch(void* const* d_in, const int* in_sizes, int n_in,
                              void* d_out, int out_size, void* d_ws, size_t ws_size,
                              hipStream_t stream) {
    const float* x = (const float*)d_in[0];
    const int* ei = (const int*)d_in[1];
    const float* w = (const float*)d_in[2];
    const float* W1 = (const float*)d_in[5];
    const float* W2 = (const float*)d_in[6];
    const float* Wo = (const float*)d_in[7];
    const float* Wn = (const float*)d_in[8];
    const float* gamma = (const float*)d_in[9];
    const float* beta = (const float*)d_in[10];
    float* out = (float*)d_out;

    char* ws = (char*)d_ws;
    const size_t BF16MAT = (size_t)NN * D * 2;   // 10.24 MB
    const size_t F32MAT = (size_t)NN * D * 4;    // 20.48 MB
    size_t off = 0;
    ushort* h = (ushort*)(ws + off);   off += BF16MAT;                 // bf16
    float* xn = (float*)(ws + off);    off += F32MAT;                  // fp32
    float* stats = (float*)(ws + off); off += 2 * GG * D * 4 + 256;
    short* WT = (short*)(ws + off);    off += 4 * (size_t)D * D * 2;
    int* deg = (int*)(ws + off);       off += (size_t)NN * 4;
    int* ov = (int*)(ws + off);        off += (1 + OVCAP) * 4 + 252; off &= ~(size_t)255;
    int2* csr = (int2*)(ws + off);     // NN*CAP*8 = 10.24 MB; total ~41.5 MB

    const int MM_GRID = NN / 64;  // 625

    wtrans_k<<<4, 256, 0, stream>>>(W1, W2, Wo, Wn, WT);
    // h = leaky(x@W1) @ W2 (fused, t1 lives in LDS)
    mlp_k<<<MM_GRID, 256, 0, stream>>>(x, WT, WT + D * D, h);
    // CSR build + gather
    hipMemsetAsync(deg, 0, (size_t)NN * 4, stream);
    hipMemsetAsync(ov, 0, (1 + OVCAP) * 4, stream);
    hipMemsetAsync(stats, 0, 2 * GG * D * 4, stream);
    fill_k<<<EE / (256 * 4), 256, 0, stream>>>(ei, w, deg, csr, ov);
    gather_k<<<NN / 8, 256, 0, stream>>>(h, deg, csr, xn);
    overflow_k<<<1, 256, 0, stream>>>(h, ei, w, ov, xn);
    // out = h@Wo + leaky(xn)@Wn
    mm_k<1, 0, 1, 0, 1, 0, 0><<<MM_GRID, 256, 0, stream>>>(h, WT + 2 * D * D, xn, WT + 3 * D * D, out);
    // GraphNorm
    stats_k<<<GG * 50, 256, 0, stream>>>(out, stats);
    norm_k<<<(NN * D / 4) / 256, 256, 0, stream>>>(out, stats, gamma, beta);
}